// Round 19
// baseline (63.245 us; speedup 1.0000x reference)
//
#include <hip/hip_runtime.h>
#include <math.h>

#define NB 2
#define NL 256
#define NH 768
#define NI 1536
#define NM (NB * NL)   // 512

typedef __attribute__((ext_vector_type(8))) short bf16x8;
typedef __attribute__((ext_vector_type(4))) float f32x4;
typedef __attribute__((ext_vector_type(4))) unsigned int u32x4;

#if __has_builtin(__builtin_amdgcn_exp2f)
#define FAST_EXP2(x) __builtin_amdgcn_exp2f(x)
#else
#define FAST_EXP2(x) exp2f(x)
#endif
#if __has_builtin(__builtin_amdgcn_rcpf)
#define FAST_RCP(x) __builtin_amdgcn_rcpf(x)
#else
#define FAST_RCP(x) (1.0f / (x))
#endif

#define KQ (-2.4554669f)   // -1.702 * log2(e)  (quick-gelu exponent)

// fp32 -> bf16 round-to-nearest-even, packed pair (lo in low 16, hi in high 16)
__device__ __forceinline__ unsigned short f2bf(float f) {
  unsigned int u = __builtin_bit_cast(unsigned int, f);
  u += 0x7FFFu + ((u >> 16) & 1u);
  return (unsigned short)(u >> 16);
}
__device__ __forceinline__ unsigned int pack2(float lo, float hi) {
  return (unsigned int)f2bf(lo) | ((unsigned int)f2bf(hi) << 16);
}
__device__ __forceinline__ float bits2f(unsigned int u) {
  return __builtin_bit_cast(float, u);
}

// ---------------------------------------------------------------------------
// Kernel 2+1 fused (unchanged from R18): bf16 MFMA GEMM (z=0,1) + logits (z=2).
// z=0: aOut[m][n] = hs @ w1[:H] + b1
// z=1: cE[b][i][t] = u32( bf16(c*w2[i]) | bf16(exp2(KQ*c))<<16 )
// z=2: 128 blocks x 512 thr, 4 rows each -> start/end logits.
// ---------------------------------------------------------------------------
__global__ __launch_bounds__(512) void gemm_mfma(
    const float* __restrict__ hs, const float* __restrict__ w1,
    const float* __restrict__ b1, const float* __restrict__ w2,
    const float* __restrict__ sw, const float* __restrict__ sb,
    const float* __restrict__ ew, const float* __restrict__ eb,
    float* __restrict__ aOut, unsigned int* __restrict__ cE,
    float* __restrict__ out) {
  constexpr int BM = 64, BN = 96, BK = 32;
  __shared__ short A_lds[BM * BK];   // [64][32] swizzled, 4 KB
  __shared__ short B_lds[BN * BK];   // [96][32] swizzled, 6 KB
  __shared__ float ls_s[4][2], ls_e[4][2];

  const int tid = threadIdx.x;

  if (blockIdx.z == 2) {
    const int gid = blockIdx.x * 16 + blockIdx.y;
    const int g = tid >> 7;          // row group 0..3
    const int l = tid & 127;
    const int m = gid * 4 + g;
    const float* row = hs + (size_t)m * NH;
    float accs = 0.f, acce = 0.f;
    for (int h = l; h < NH; h += 128) {
      float v = row[h];
      accs = fmaf(v, sw[h], accs);
      acce = fmaf(v, ew[h], acce);
    }
    for (int off = 32; off > 0; off >>= 1) {
      accs += __shfl_down(accs, off, 64);
      acce += __shfl_down(acce, off, 64);
    }
    if ((tid & 63) == 0) {
      ls_s[g][(tid >> 6) & 1] = accs;
      ls_e[g][(tid >> 6) & 1] = acce;
    }
    __syncthreads();
    if (l == 0) {
      out[m]      = ls_s[g][0] + ls_s[g][1] + sb[0];
      out[NM + m] = ls_e[g][0] + ls_e[g][1] + eb[0];
    }
    return;
  }

  const int mode = blockIdx.z;
  const float* __restrict__ W = w1 + (size_t)mode * NH * NI;
  const int m0 = blockIdx.x * BM;
  const int n0 = blockIdx.y * BN;
  const int lane = tid & 63;
  const int wid = tid >> 6;          // 0..7
  const int wr = wid >> 1;           // 0..3  (m quarter, 16 rows)
  const int wc = wid & 1;            // 0..1  (n half, 48 cols)

  const int ar  = tid >> 3;          // A row 0..63
  const int ac  = (tid & 7) * 4;     // A k-offset, float4
  const int bkq = (tid >> 5) * 2;    // B k-offset, 2 rows
  const int bnl = tid & 31;          // B n-lane

  f32x4 acc[3] = {};

  float4 av = *reinterpret_cast<const float4*>(hs + (size_t)(m0 + ar) * NH + ac);
  float bv[2][3];
#pragma unroll
  for (int j = 0; j < 2; ++j) {
    const float* pb = W + (size_t)(bkq + j) * NI + n0 + bnl;
#pragma unroll
    for (int nn = 0; nn < 3; ++nn) bv[j][nn] = pb[nn * 32];
  }

  for (int k0 = 0; k0 < NH; k0 += BK) {
    __syncthreads();
    {
      uint2 v;
      v.x = pack2(av.x, av.y);
      v.y = pack2(av.z, av.w);
      const int off = ar * 64 + ((((ac >> 3) & 3) ^ (ar & 3)) << 4) + ((ac & 4) << 1);
      *reinterpret_cast<uint2*>(reinterpret_cast<char*>(A_lds) + off) = v;
    }
#pragma unroll
    for (int nn = 0; nn < 3; ++nn) {
      const int n = bnl + nn * 32;
      unsigned int v = pack2(bv[0][nn], bv[1][nn]);
      const int off = n * 64 + (((bkq >> 3) ^ (n & 3)) << 4) + ((bkq * 2) & 12);
      *reinterpret_cast<unsigned int*>(reinterpret_cast<char*>(B_lds) + off) = v;
    }
    __syncthreads();
    const int kn = k0 + BK;
    if (kn < NH) {
      av = *reinterpret_cast<const float4*>(hs + (size_t)(m0 + ar) * NH + kn + ac);
#pragma unroll
      for (int j = 0; j < 2; ++j) {
        const float* pb = W + (size_t)(kn + bkq + j) * NI + n0 + bnl;
#pragma unroll
        for (int nn = 0; nn < 3; ++nn) bv[j][nn] = pb[nn * 32];
      }
    }
    const int lr = lane & 15, ls = lane >> 4;
    bf16x8 af, bf[3];
    {
      const int row = wr * 16 + lr;
      const int off = row * 64 + ((ls ^ (row & 3)) << 4);
      af = *reinterpret_cast<const bf16x8*>(reinterpret_cast<const char*>(A_lds) + off);
    }
#pragma unroll
    for (int nt = 0; nt < 3; ++nt) {
      const int nrow = wc * 48 + nt * 16 + lr;
      const int off = nrow * 64 + ((ls ^ (nrow & 3)) << 4);
      bf[nt] = *reinterpret_cast<const bf16x8*>(reinterpret_cast<const char*>(B_lds) + off);
    }
#pragma unroll
    for (int nt = 0; nt < 3; ++nt)
      acc[nt] = __builtin_amdgcn_mfma_f32_16x16x32_bf16(af, bf[nt], acc[nt], 0, 0, 0);
  }

  const int lr = lane & 15, lq = lane >> 4;
  if (mode == 0) {
    const int mb = m0 + wr * 16 + lq * 4;
#pragma unroll
    for (int nt = 0; nt < 3; ++nt) {
      const int n = n0 + wc * 48 + nt * 16 + lr;
      const float bias = b1[n];
#pragma unroll
      for (int r = 0; r < 4; ++r)
        aOut[(size_t)(mb + r) * NI + n] = acc[nt][r] + bias;
    }
  } else {
    const int b = m0 >> 8;
    const int tb = (m0 & (NL - 1)) + wr * 16 + lq * 4;
#pragma unroll
    for (int nt = 0; nt < 3; ++nt) {
      const int i = n0 + wc * 48 + nt * 16 + lr;
      const float wv = w2[i];
      unsigned int* dst = cE + ((size_t)b * NI + i) * NL + tb;
      f32x4 v = acc[nt];
      u32x4 pk;
      pk.x = pack2(v[0] * wv, FAST_EXP2(KQ * v[0]));
      pk.y = pack2(v[1] * wv, FAST_EXP2(KQ * v[1]));
      pk.z = pack2(v[2] * wv, FAST_EXP2(KQ * v[2]));
      pk.w = pack2(v[3] * wv, FAST_EXP2(KQ * v[3]));
      *reinterpret_cast<u32x4*>(dst) = pk;
    }
  }
}

// ---------------------------------------------------------------------------
// Kernel 3: span logits v15 — s-QUAD reuse (16 elems/lane-iter = 4t x 4s).
// Per iter: ONE uint4 cE load (4 t packed (cw,Ec)) + ONE uint4 LDS load
// ((a*w, Ea) for 4 s, bf16-packed) -> 16 gelu evals. cE traffic HALVED
// vs R18 (201 MB). LDS entry/i = 16 B -> 24.6 KB, 5 blocks/CU.
// Grid 1024 = 128 s-quads x 8 t-eighths, 256 thr: t8 = tid&7, q = tid>>3.
// ---------------------------------------------------------------------------
__global__ __launch_bounds__(256, 2) void span_kernel(
    const float* __restrict__ aRow,       // [M][I], b1 folded
    const unsigned int* __restrict__ cE,  // [B][I][L] packed (cw, Ec)
    const float* __restrict__ w2,
    const float* __restrict__ b2,
    float* __restrict__ out) {
  const int blk = blockIdx.x;          // 0..1023
  const int sg  = blk >> 3;            // s-quad 0..127
  const int te  = blk & 7;             // t-eighth
  const int s0  = sg * 4;
  const int b   = s0 >> 8;
  const int tbase = te * 32;
  const int tid = threadIdx.x;
  const int t8  = tid & 7;             // 8 lanes x 4 t = 32 t
  const int q   = tid >> 3;            // 0..31, 48-i chunk each
  const int lane = tid & 63;
  const int w    = tid >> 6;           // wave 0..3

  __shared__ u32x4 aw4[NI + 32];       // (aw01, aw23, Ea01, Ea23) bf16-packed: 24.6 KB
  __shared__ float4 red[4][4][8];      // [wave][s][t8] 2 KB

  const float* a0p = aRow + (size_t)s0 * NI;
  for (int i = tid; i < NI; i += 256) {
    float a0 = a0p[i], a1 = a0p[NI + i], a2 = a0p[2 * NI + i], a3 = a0p[3 * NI + i];
    float wv = w2[i];
    u32x4 pk;
    pk.x = pack2(a0 * wv, a1 * wv);
    pk.y = pack2(a2 * wv, a3 * wv);
    pk.z = pack2(FAST_EXP2(KQ * a0), FAST_EXP2(KQ * a1));
    pk.w = pack2(FAST_EXP2(KQ * a2), FAST_EXP2(KQ * a3));
    aw4[i + i / 48] = pk;
  }
  __syncthreads();

  const unsigned int* cb = cE + ((size_t)b * NI + q * 48) * NL + tbase + t8 * 4;
  const u32x4* awq = aw4 + q * 49;

  f32x4 acc0 = {0.f, 0.f, 0.f, 0.f};   // s0, t0..3
  f32x4 acc1 = {0.f, 0.f, 0.f, 0.f};   // s1
  f32x4 acc2 = {0.f, 0.f, 0.f, 0.f};   // s2
  f32x4 acc3 = {0.f, 0.f, 0.f, 0.f};   // s3

#define SBLK(ACC, AWU, EAU, HALF)                                   \
  {                                                                 \
    float aw_ = bits2f(HALF ? ((AWU) & 0xFFFF0000u) : ((AWU) << 16)); \
    float Ea_ = bits2f(HALF ? ((EAU) & 0xFFFF0000u) : ((EAU) << 16)); \
    float n0 = aw_ + cw0, n1 = aw_ + cw1;                           \
    float n2 = aw_ + cw2, n3 = aw_ + cw3;                           \
    float d0 = fmaf(Ea_, E0, 1.f), d1 = fmaf(Ea_, E1, 1.f);         \
    float d2 = fmaf(Ea_, E2, 1.f), d3 = fmaf(Ea_, E3, 1.f);         \
    float mA = d0 * d1, mB = d2 * d3;                               \
    float r = FAST_RCP(mA * mB);                                    \
    float rA = r * mB, rB = r * mA;                                 \
    ACC[0] = fmaf(n0, rA * d1, ACC[0]);                             \
    ACC[1] = fmaf(n1, rA * d0, ACC[1]);                             \
    ACC[2] = fmaf(n2, rB * d3, ACC[2]);                             \
    ACC[3] = fmaf(n3, rB * d2, ACC[3]);                             \
  }

#pragma unroll 4
  for (int ii = 0; ii < 48; ++ii) {
    u32x4 cv = *reinterpret_cast<const u32x4*>(cb);   // 4 packed (cw,Ec)
    u32x4 A = awq[ii];                                // (aw01, aw23, Ea01, Ea23)
    float cw0 = bits2f(cv.x << 16), E0 = bits2f(cv.x & 0xFFFF0000u);
    float cw1 = bits2f(cv.y << 16), E1 = bits2f(cv.y & 0xFFFF0000u);
    float cw2 = bits2f(cv.z << 16), E2 = bits2f(cv.z & 0xFFFF0000u);
    float cw3 = bits2f(cv.w << 16), E3 = bits2f(cv.w & 0xFFFF0000u);
    SBLK(acc0, A.x, A.z, 0)
    SBLK(acc1, A.x, A.z, 1)
    SBLK(acc2, A.y, A.w, 0)
    SBLK(acc3, A.y, A.w, 1)
    cb += NL;
  }
#undef SBLK

  // fold lane bits 3,4,5 (q-subgroups within wave)
#pragma unroll
  for (int k = 0; k < 4; ++k) {
    acc0[k] += __shfl_xor(acc0[k], 8, 64);
    acc0[k] += __shfl_xor(acc0[k], 16, 64);
    acc0[k] += __shfl_xor(acc0[k], 32, 64);
    acc1[k] += __shfl_xor(acc1[k], 8, 64);
    acc1[k] += __shfl_xor(acc1[k], 16, 64);
    acc1[k] += __shfl_xor(acc1[k], 32, 64);
    acc2[k] += __shfl_xor(acc2[k], 8, 64);
    acc2[k] += __shfl_xor(acc2[k], 16, 64);
    acc2[k] += __shfl_xor(acc2[k], 32, 64);
    acc3[k] += __shfl_xor(acc3[k], 8, 64);
    acc3[k] += __shfl_xor(acc3[k], 16, 64);
    acc3[k] += __shfl_xor(acc3[k], 32, 64);
  }
  if (lane < 8) {
    red[w][0][lane] = make_float4(acc0[0], acc0[1], acc0[2], acc0[3]);
    red[w][1][lane] = make_float4(acc1[0], acc1[1], acc1[2], acc1[3]);
    red[w][2][lane] = make_float4(acc2[0], acc2[1], acc2[2], acc2[3]);
    red[w][3][lane] = make_float4(acc3[0], acc3[1], acc3[2], acc3[3]);
  }
  __syncthreads();
  if (tid < 32) {
    const int s = tid >> 3;
    const int tt = tid & 7;
    float4 v0 = red[0][s][tt];
    float4 v1 = red[1][s][tt];
    float4 v2 = red[2][s][tt];
    float4 v3 = red[3][s][tt];
    const float bb = b2[0];
    float4 o;
    o.x = (v0.x + v1.x) + (v2.x + v3.x) + bb;
    o.y = (v0.y + v1.y) + (v2.y + v3.y) + bb;
    o.z = (v0.z + v1.z) + (v2.z + v3.z) + bb;
    o.w = (v0.w + v1.w) + (v2.w + v3.w) + bb;
    *reinterpret_cast<float4*>(out + 2 * NM + (size_t)(s0 + s) * NL + tbase + tt * 4) = o;
  }
}

// ---------------------------------------------------------------------------
extern "C" void kernel_launch(void* const* d_in, const int* in_sizes, int n_in,
                              void* d_out, int out_size, void* d_ws, size_t ws_size,
                              hipStream_t stream) {
  const float* hs = (const float*)d_in[0];
  const float* sw = (const float*)d_in[1];
  const float* sb = (const float*)d_in[2];
  const float* ew = (const float*)d_in[3];
  const float* eb = (const float*)d_in[4];
  const float* w1 = (const float*)d_in[5];
  const float* b1 = (const float*)d_in[6];
  const float* w2 = (const float*)d_in[7];
  const float* b2 = (const float*)d_in[8];
  float* out = (float*)d_out;

  float* a = (float*)d_ws;                                      // M*I f32 = 3 MB
  unsigned int* cE = (unsigned int*)((float*)d_ws + (size_t)NM * NI);  // 3 MB

  dim3 ggrid(NM / 64, NI / 96, 3);   // z=0: a, z=1: cE, z=2: logits
  gemm_mfma<<<ggrid, 512, 0, stream>>>(hs, w1, b1, w2, sw, sb, ew, eb, a, cE, out);

  span_kernel<<<1024, 256, 0, stream>>>(a, cE, w2, b2, out);
}

// Round 20
// 62.201 us; speedup vs baseline: 1.0168x; 1.0168x over previous
//
#include <hip/hip_runtime.h>
#include <math.h>

#define NB 2
#define NL 256
#define NH 768
#define NI 1536
#define NM (NB * NL)   // 512

typedef __attribute__((ext_vector_type(8))) short bf16x8;
typedef __attribute__((ext_vector_type(4))) float f32x4;
typedef __attribute__((ext_vector_type(4))) unsigned int u32x4;

#if __has_builtin(__builtin_amdgcn_exp2f)
#define FAST_EXP2(x) __builtin_amdgcn_exp2f(x)
#else
#define FAST_EXP2(x) exp2f(x)
#endif
#if __has_builtin(__builtin_amdgcn_rcpf)
#define FAST_RCP(x) __builtin_amdgcn_rcpf(x)
#else
#define FAST_RCP(x) (1.0f / (x))
#endif

#define KQ (-2.4554669f)   // -1.702 * log2(e)  (quick-gelu exponent)

// fp32 -> bf16 round-to-nearest-even, packed pair (lo in low 16, hi in high 16)
__device__ __forceinline__ unsigned short f2bf(float f) {
  unsigned int u = __builtin_bit_cast(unsigned int, f);
  u += 0x7FFFu + ((u >> 16) & 1u);
  return (unsigned short)(u >> 16);
}
__device__ __forceinline__ unsigned int pack2(float lo, float hi) {
  return (unsigned int)f2bf(lo) | ((unsigned int)f2bf(hi) << 16);
}
__device__ __forceinline__ float bits2f(unsigned int u) {
  return __builtin_bit_cast(float, u);
}

// ---------------------------------------------------------------------------
// Kernel 2+1 fused: bf16 MFMA GEMM (z=0,1) + start/end logits (z=2).
// z=0: aOut[m][n] = hs @ w1[:H] + b1
// z=1: cE[b][i][t] = u32( bf16(c*w2[i]) | bf16(exp2(KQ*c))<<16 )
// z=2: 128 blocks x 512 thr, 4 rows each -> start/end logits.
// ---------------------------------------------------------------------------
__global__ __launch_bounds__(512) void gemm_mfma(
    const float* __restrict__ hs, const float* __restrict__ w1,
    const float* __restrict__ b1, const float* __restrict__ w2,
    const float* __restrict__ sw, const float* __restrict__ sb,
    const float* __restrict__ ew, const float* __restrict__ eb,
    float* __restrict__ aOut, unsigned int* __restrict__ cE,
    float* __restrict__ out) {
  constexpr int BM = 64, BN = 96, BK = 32;
  __shared__ short A_lds[BM * BK];   // [64][32] swizzled, 4 KB
  __shared__ short B_lds[BN * BK];   // [96][32] swizzled, 6 KB
  __shared__ float ls_s[4][2], ls_e[4][2];

  const int tid = threadIdx.x;

  if (blockIdx.z == 2) {
    const int gid = blockIdx.x * 16 + blockIdx.y;
    const int g = tid >> 7;          // row group 0..3
    const int l = tid & 127;
    const int m = gid * 4 + g;
    const float* row = hs + (size_t)m * NH;
    float accs = 0.f, acce = 0.f;
    for (int h = l; h < NH; h += 128) {
      float v = row[h];
      accs = fmaf(v, sw[h], accs);
      acce = fmaf(v, ew[h], acce);
    }
    for (int off = 32; off > 0; off >>= 1) {
      accs += __shfl_down(accs, off, 64);
      acce += __shfl_down(acce, off, 64);
    }
    if ((tid & 63) == 0) {
      ls_s[g][(tid >> 6) & 1] = accs;
      ls_e[g][(tid >> 6) & 1] = acce;
    }
    __syncthreads();
    if (l == 0) {
      out[m]      = ls_s[g][0] + ls_s[g][1] + sb[0];
      out[NM + m] = ls_e[g][0] + ls_e[g][1] + eb[0];
    }
    return;
  }

  const int mode = blockIdx.z;
  const float* __restrict__ W = w1 + (size_t)mode * NH * NI;
  const int m0 = blockIdx.x * BM;
  const int n0 = blockIdx.y * BN;
  const int lane = tid & 63;
  const int wid = tid >> 6;          // 0..7
  const int wr = wid >> 1;           // 0..3  (m quarter, 16 rows)
  const int wc = wid & 1;            // 0..1  (n half, 48 cols)

  const int ar  = tid >> 3;          // A row 0..63
  const int ac  = (tid & 7) * 4;     // A k-offset, float4
  const int bkq = (tid >> 5) * 2;    // B k-offset, 2 rows
  const int bnl = tid & 31;          // B n-lane

  f32x4 acc[3] = {};

  float4 av = *reinterpret_cast<const float4*>(hs + (size_t)(m0 + ar) * NH + ac);
  float bv[2][3];
#pragma unroll
  for (int j = 0; j < 2; ++j) {
    const float* pb = W + (size_t)(bkq + j) * NI + n0 + bnl;
#pragma unroll
    for (int nn = 0; nn < 3; ++nn) bv[j][nn] = pb[nn * 32];
  }

  for (int k0 = 0; k0 < NH; k0 += BK) {
    __syncthreads();
    {
      uint2 v;
      v.x = pack2(av.x, av.y);
      v.y = pack2(av.z, av.w);
      const int off = ar * 64 + ((((ac >> 3) & 3) ^ (ar & 3)) << 4) + ((ac & 4) << 1);
      *reinterpret_cast<uint2*>(reinterpret_cast<char*>(A_lds) + off) = v;
    }
#pragma unroll
    for (int nn = 0; nn < 3; ++nn) {
      const int n = bnl + nn * 32;
      unsigned int v = pack2(bv[0][nn], bv[1][nn]);
      const int off = n * 64 + (((bkq >> 3) ^ (n & 3)) << 4) + ((bkq * 2) & 12);
      *reinterpret_cast<unsigned int*>(reinterpret_cast<char*>(B_lds) + off) = v;
    }
    __syncthreads();
    const int kn = k0 + BK;
    if (kn < NH) {
      av = *reinterpret_cast<const float4*>(hs + (size_t)(m0 + ar) * NH + kn + ac);
#pragma unroll
      for (int j = 0; j < 2; ++j) {
        const float* pb = W + (size_t)(kn + bkq + j) * NI + n0 + bnl;
#pragma unroll
        for (int nn = 0; nn < 3; ++nn) bv[j][nn] = pb[nn * 32];
      }
    }
    const int lr = lane & 15, ls = lane >> 4;
    bf16x8 af, bf[3];
    {
      const int row = wr * 16 + lr;
      const int off = row * 64 + ((ls ^ (row & 3)) << 4);
      af = *reinterpret_cast<const bf16x8*>(reinterpret_cast<const char*>(A_lds) + off);
    }
#pragma unroll
    for (int nt = 0; nt < 3; ++nt) {
      const int nrow = wc * 48 + nt * 16 + lr;
      const int off = nrow * 64 + ((ls ^ (nrow & 3)) << 4);
      bf[nt] = *reinterpret_cast<const bf16x8*>(reinterpret_cast<const char*>(B_lds) + off);
    }
#pragma unroll
    for (int nt = 0; nt < 3; ++nt)
      acc[nt] = __builtin_amdgcn_mfma_f32_16x16x32_bf16(af, bf[nt], acc[nt], 0, 0, 0);
  }

  const int lr = lane & 15, lq = lane >> 4;
  if (mode == 0) {
    const int mb = m0 + wr * 16 + lq * 4;
#pragma unroll
    for (int nt = 0; nt < 3; ++nt) {
      const int n = n0 + wc * 48 + nt * 16 + lr;
      const float bias = b1[n];
#pragma unroll
      for (int r = 0; r < 4; ++r)
        aOut[(size_t)(mb + r) * NI + n] = acc[nt][r] + bias;
    }
  } else {
    // packed (bf16(c*w2) | bf16(exp2(KQ*c))<<16) per t; acc[nt][r] is t = tb+r
    const int b = m0 >> 8;
    const int tb = (m0 & (NL - 1)) + wr * 16 + lq * 4;
#pragma unroll
    for (int nt = 0; nt < 3; ++nt) {
      const int i = n0 + wc * 48 + nt * 16 + lr;
      const float wv = w2[i];
      unsigned int* dst = cE + ((size_t)b * NI + i) * NL + tb;
      f32x4 v = acc[nt];
      u32x4 pk;
      pk.x = pack2(v[0] * wv, FAST_EXP2(KQ * v[0]));
      pk.y = pack2(v[1] * wv, FAST_EXP2(KQ * v[1]));
      pk.z = pack2(v[2] * wv, FAST_EXP2(KQ * v[2]));
      pk.w = pack2(v[3] * wv, FAST_EXP2(KQ * v[3]));
      *reinterpret_cast<u32x4*>(dst) = pk;
    }
  }
}

// ---------------------------------------------------------------------------
// Kernel 3: span logits v14 (R18-best) — factorized exp, w2 folded,
// bf16-PACKED cE. Each cE element = u32(bf16(cw) | bf16(Ec)<<16).
// Per iter: 8 elems (4 t x 2 s) = ONE uint4 global load + ONE float4 LDS
// read + 48 VALU + 2 rcp.
// Grid 2048 = 256 s-pairs x 8 t-eighths, 256 thr: t8 = tid&7, q = tid>>3.
// ---------------------------------------------------------------------------
__global__ __launch_bounds__(256, 2) void span_kernel(
    const float* __restrict__ aRow,   // [M][I], b1 folded
    const unsigned int* __restrict__ cE,  // [B][I][L] packed
    const float* __restrict__ w2,
    const float* __restrict__ b2,
    float* __restrict__ out) {
  const int blk = blockIdx.x;          // 0..2047
  const int sg  = blk >> 3;            // s-pair 0..255
  const int te  = blk & 7;             // t-eighth
  const int s0  = sg * 2;
  const int b   = s0 >> 8;
  const int tbase = te * 32;
  const int tid = threadIdx.x;
  const int t8  = tid & 7;             // 8 lanes x 4 t = 32 t
  const int q   = tid >> 3;            // 0..31, 48-i chunk each
  const int lane = tid & 63;
  const int w    = tid >> 6;           // wave 0..3

  __shared__ float4 aw4[NI + 32];      // (a0*w, a1*w, Ea0, Ea1), skew i+i/48: 25 KB
  __shared__ float4 red[4][2][8];      // 1 KB

  const float* a0p = aRow + (size_t)s0 * NI;
  const float* a1p = a0p + NI;
  for (int i = tid; i < NI; i += 256) {
    float a0 = a0p[i], a1 = a1p[i], wv = w2[i];
    aw4[i + i / 48] = make_float4(a0 * wv, a1 * wv,
                                  FAST_EXP2(KQ * a0), FAST_EXP2(KQ * a1));
  }
  __syncthreads();

  const unsigned int* cb = cE + ((size_t)b * NI + q * 48) * NL + tbase + t8 * 4;
  const float4* awq = aw4 + q * 49;

  f32x4 acc0 = {0.f, 0.f, 0.f, 0.f};   // s0, t0..3
  f32x4 acc1 = {0.f, 0.f, 0.f, 0.f};   // s1, t0..3

#pragma unroll 4
  for (int ii = 0; ii < 48; ++ii) {
    u32x4 cv = *reinterpret_cast<const u32x4*>(cb);   // 4 packed (cw,E)
    float4 A = awq[ii];                 // (a0w, a1w, Ea0, Ea1)
    float cw0 = bits2f(cv.x << 16), E0 = bits2f(cv.x & 0xFFFF0000u);
    float cw1 = bits2f(cv.y << 16), E1 = bits2f(cv.y & 0xFFFF0000u);
    float cw2 = bits2f(cv.z << 16), E2 = bits2f(cv.z & 0xFFFF0000u);
    float cw3 = bits2f(cv.w << 16), E3 = bits2f(cv.w & 0xFFFF0000u);
    // s = 0
    {
      float n0 = A.x + cw0, n1 = A.x + cw1;
      float n2 = A.x + cw2, n3 = A.x + cw3;
      float d0 = fmaf(A.z, E0, 1.f), d1 = fmaf(A.z, E1, 1.f);
      float d2 = fmaf(A.z, E2, 1.f), d3 = fmaf(A.z, E3, 1.f);
      float mA = d0 * d1, mB = d2 * d3;
      float r = FAST_RCP(mA * mB);
      float rA = r * mB, rB = r * mA;
      acc0[0] = fmaf(n0, rA * d1, acc0[0]);
      acc0[1] = fmaf(n1, rA * d0, acc0[1]);
      acc0[2] = fmaf(n2, rB * d3, acc0[2]);
      acc0[3] = fmaf(n3, rB * d2, acc0[3]);
    }
    // s = 1
    {
      float n0 = A.y + cw0, n1 = A.y + cw1;
      float n2 = A.y + cw2, n3 = A.y + cw3;
      float d0 = fmaf(A.w, E0, 1.f), d1 = fmaf(A.w, E1, 1.f);
      float d2 = fmaf(A.w, E2, 1.f), d3 = fmaf(A.w, E3, 1.f);
      float mA = d0 * d1, mB = d2 * d3;
      float r = FAST_RCP(mA * mB);
      float rA = r * mB, rB = r * mA;
      acc1[0] = fmaf(n0, rA * d1, acc1[0]);
      acc1[1] = fmaf(n1, rA * d0, acc1[1]);
      acc1[2] = fmaf(n2, rB * d3, acc1[2]);
      acc1[3] = fmaf(n3, rB * d2, acc1[3]);
    }
    cb += NL;
  }

  // fold lane bits 3,4,5 (q-subgroups within wave)
#pragma unroll
  for (int k = 0; k < 4; ++k) {
    acc0[k] += __shfl_xor(acc0[k], 8, 64);
    acc0[k] += __shfl_xor(acc0[k], 16, 64);
    acc0[k] += __shfl_xor(acc0[k], 32, 64);
    acc1[k] += __shfl_xor(acc1[k], 8, 64);
    acc1[k] += __shfl_xor(acc1[k], 16, 64);
    acc1[k] += __shfl_xor(acc1[k], 32, 64);
  }
  if (lane < 8) {
    red[w][0][lane] = make_float4(acc0[0], acc0[1], acc0[2], acc0[3]);
    red[w][1][lane] = make_float4(acc1[0], acc1[1], acc1[2], acc1[3]);
  }
  __syncthreads();
  if (tid < 16) {
    const int s = tid >> 3;
    const int tt = tid & 7;
    float4 v0 = red[0][s][tt];
    float4 v1 = red[1][s][tt];
    float4 v2 = red[2][s][tt];
    float4 v3 = red[3][s][tt];
    const float bb = b2[0];
    float4 o;
    o.x = (v0.x + v1.x) + (v2.x + v3.x) + bb;
    o.y = (v0.y + v1.y) + (v2.y + v3.y) + bb;
    o.z = (v0.z + v1.z) + (v2.z + v3.z) + bb;
    o.w = (v0.w + v1.w) + (v2.w + v3.w) + bb;
    *reinterpret_cast<float4*>(out + 2 * NM + (size_t)(s0 + s) * NL + tbase + tt * 4) = o;
  }
}

// ---------------------------------------------------------------------------
extern "C" void kernel_launch(void* const* d_in, const int* in_sizes, int n_in,
                              void* d_out, int out_size, void* d_ws, size_t ws_size,
                              hipStream_t stream) {
  const float* hs = (const float*)d_in[0];
  const float* sw = (const float*)d_in[1];
  const float* sb = (const float*)d_in[2];
  const float* ew = (const float*)d_in[3];
  const float* eb = (const float*)d_in[4];
  const float* w1 = (const float*)d_in[5];
  const float* b1 = (const float*)d_in[6];
  const float* w2 = (const float*)d_in[7];
  const float* b2 = (const float*)d_in[8];
  float* out = (float*)d_out;

  float* a = (float*)d_ws;                                      // M*I f32 = 3 MB
  unsigned int* cE = (unsigned int*)((float*)d_ws + (size_t)NM * NI);  // 3 MB

  dim3 ggrid(NM / 64, NI / 96, 3);   // z=0: a, z=1: cE, z=2: logits
  gemm_mfma<<<ggrid, 512, 0, stream>>>(hs, w1, b1, w2, sw, sb, ew, eb, a, cE, out);

  span_kernel<<<2048, 256, 0, stream>>>(a, cE, w2, b2, out);
}